// Round 6
// baseline (3361.623 us; speedup 1.0000x reference)
//
#include <hip/hip_runtime.h>

typedef _Float16 f16;
typedef _Float16 f16x8 __attribute__((ext_vector_type(8)));
typedef _Float16 f16x4 __attribute__((ext_vector_type(4)));
typedef float    f32x4 __attribute__((ext_vector_type(4)));
typedef unsigned long long u64;

// ---------------------------------------------------------------------------
// Prologue: normalize -> per-channel pixel permutation -> space_to_depth.
// Out: XA[p][c] fp16, p = img*1024 + h2*32 + w2, c = 0..191.
// ---------------------------------------------------------------------------
__global__ __launch_bounds__(256) void prologue_k(
    const float* __restrict__ x, const float* __restrict__ mu,
    const float* __restrict__ sigma, const int* __restrict__ perm,
    f16* __restrict__ A0)
{
    int gid = blockIdx.x * 256 + threadIdx.x;
    if (gid >= 8192 * 24) return;
    int c8 = gid % 24;
    int p  = gid / 24;
    int b  = p >> 10;
    int h2 = (p >> 5) & 31;
    int w2 = p & 31;
    int cc = c8 >> 3;
    int bh = c8 & 7;
    const int* pm = &perm[cc * 65536 + (h2 * 8 + bh) * 256 + w2 * 8];
    const float* xp = &x[(b * 3 + cc) * 65536];
    float m = mu[cc], rs = 1.0f / sigma[cc];
    f16 v[8];
#pragma unroll
    for (int k = 0; k < 8; ++k)
        v[k] = (f16)((xp[pm[k]] - m) * rs);
    *(f16x8*)&A0[(size_t)p * 192 + c8 * 8] = *(f16x8*)v;
}

// ---------------------------------------------------------------------------
// Weight conversion: fp32 [oc][ic][3][3] -> fp16 [tap][c8][oc][8] per conv.
// ---------------------------------------------------------------------------
__global__ __launch_bounds__(256) void wconv_k(const float* __restrict__ wf,
                                               f16* __restrict__ wh)
{
    int c   = blockIdx.y;          // conv 0..191
    int s   = c % 6;
    int s3  = s % 3;
    int icr = (s3 == 0) ? 96 : 128;
    int ocv = (s3 == 2) ? 96 : 128;
    int nc8 = icr >> 3;
    int wo  = (s3 == 0 ? 0 : (s3 == 1 ? 110592 : 258048)) + (s >= 3 ? 368640 : 0);
    int idx = blockIdx.x * 256 + threadIdx.x;
    if (idx >= nc8 * ocv) return;
    int o  = idx % ocv;
    int c8 = idx / ocv;
    size_t base = (size_t)(c / 6) * 737280 + wo;
    const float* src = &wf[base + ((size_t)o * icr + c8 * 8) * 9];
    f16 vt[9][8];
#pragma unroll
    for (int k = 0; k < 8; ++k)
#pragma unroll
        for (int t = 0; t < 9; ++t)
            vt[t][k] = (f16)src[k * 9 + t];
#pragma unroll
    for (int t = 0; t < 9; ++t)
        *(f16x8*)&wh[base + ((size_t)(t * nc8 + c8) * ocv + o) * 8] = *(f16x8*)vt[t];
}

// m fp32 [mat][o][i] -> fp16 [mat][i8][o][8]
__global__ __launch_bounds__(256) void mconv_k(const float* __restrict__ mf,
                                               f16* __restrict__ mh)
{
    int n = blockIdx.x * 256 + threadIdx.x;
    if (n >= 32 * 24 * 192) return;
    int o   = n % 192;
    int t   = n / 192;
    int i8  = t % 24;
    int mat = t / 24;
    const float* s = &mf[(size_t)mat * 36864 + o * 192 + i8 * 8];
    f16 v[8];
#pragma unroll
    for (int k = 0; k < 8; ++k) v[k] = (f16)s[k];
    *(f16x8*)&mh[(size_t)mat * 36864 + ((size_t)i8 * 192 + o) * 8] = *(f16x8*)v;
}

// biases fp32, pre-scaled by 2^-block (704 per block)
__global__ __launch_bounds__(256) void bconv_k(const float* __restrict__ bf,
                                               float* __restrict__ bs, int n)
{
    int i = blockIdx.x * 256 + threadIdx.x;
    if (i < n) bs[i] = ldexpf(bf[i], -(i / 704));
}

// ---------------------------------------------------------------------------
// Agent-scope activation access (coherent across XCDs, no cache fences).
// ---------------------------------------------------------------------------
__device__ __forceinline__ f16x8 ld_act16(const f16* p)
{
    u64* q = (u64*)p;
    union { u64 u[2]; f16x8 v; } c;
    c.u[0] = __hip_atomic_load(q,     __ATOMIC_RELAXED, __HIP_MEMORY_SCOPE_AGENT);
    c.u[1] = __hip_atomic_load(q + 1, __ATOMIC_RELAXED, __HIP_MEMORY_SCOPE_AGENT);
    return c.v;
}
__device__ __forceinline__ f16x4 ld_act8(const f16* p)
{
    union { u64 u; f16x4 v; } c;
    c.u = __hip_atomic_load((u64*)p, __ATOMIC_RELAXED, __HIP_MEMORY_SCOPE_AGENT);
    return c.v;
}
__device__ __forceinline__ void st_act8(f16* p, f16x4 v)
{
    union { u64 u; f16x4 v; } c;
    c.v = v;
    __hip_atomic_store((u64*)p, c.u, __ATOMIC_RELAXED, __HIP_MEMORY_SCOPE_AGENT);
}

// ---------------------------------------------------------------------------
// Per-image barrier (32 WGs), fence-free: vmcnt drain + monotone counter.
// ---------------------------------------------------------------------------
__device__ __forceinline__ void img_barrier(unsigned* ctr, unsigned target)
{
    asm volatile("s_waitcnt vmcnt(0) lgkmcnt(0)" ::: "memory");
    __syncthreads();
    if (threadIdx.x == 0) {
        __hip_atomic_fetch_add(ctr, 1u, __ATOMIC_RELAXED, __HIP_MEMORY_SCOPE_AGENT);
        while (__hip_atomic_load(ctr, __ATOMIC_RELAXED, __HIP_MEMORY_SCOPE_AGENT) < target)
            __builtin_amdgcn_s_sleep(4);
    }
    __syncthreads();
}

// ---------------------------------------------------------------------------
// One layer. WG = 4 waves; tile = 4 rows x OCW oc (all waves same oc slice ->
// W dedups in L1). X staged once in swizzled LDS; W in registers, 2 taps ahead.
// ---------------------------------------------------------------------------
template<int MMv, int OCV, int NC8R, int TAPS, bool RELU, bool ACCUM, bool OUT32>
__device__ __forceinline__ void layer(char* lds, int img, int local,
    const f16* __restrict__ Xin, int ICS,
    const f16* __restrict__ W, const float* __restrict__ bias,
    f16* __restrict__ Out, int OCS, float* __restrict__ Out32, float scale)
{
    constexpr int OCW  = MMv * 16;
    constexpr int NG   = OCV / OCW;               // oc groups (4,3,4)
    constexpr int PAD  = (TAPS == 9) ? 1 : 0;
    constexpr int ROWS = 4 + 2 * PAD;             // 6 or 4
    constexpr int WW   = 32 + 2 * PAD;            // 34 or 32
    constexpr int NC8P = (NC8R + 7) & ~7;         // slot-space granules
    constexpr int KC   = NC8R / 4;                // K32 chunks
    constexpr int S    = ROWS * WW * NC8P;

    const int tid   = threadIdx.x;
    const int ocidx = local & 3;
    if (ocidx >= NG) return;                      // idle WG (conv3)
    const int rowg = local >> 2;                  // 0..7
    const int r0   = rowg * 4;
    const int lane = tid & 63, wave = tid >> 6;
    const int lq   = lane >> 4, ln = lane & 15;
    const int ocg  = ocidx * OCW;

    // ---- W loader: tap slice -> named register buffer ----
    auto loadw = [&](f16x8 (&dst)[KC][MMv], int tap) {
#pragma unroll
        for (int kc = 0; kc < KC; ++kc)
#pragma unroll
            for (int m = 0; m < MMv; ++m)
                dst[kc][m] = *(const f16x8*)&W[
                    ((size_t)(tap * NC8R + kc * 4 + lq) * OCV + ocg + m * 16 + ln) * 8];
    };
    f16x8 w0[KC][MMv], w1[KC][MMv], w2[KC][MMv];
    loadw(w0, 0);
    if (TAPS > 1) loadw(w1, 1);

    // ---- stage X (4 rows + halo, full IC, XOR-swizzled slots) ----
    for (int s = tid; s < S; s += 256) {
        int gslot = s % NC8P;
        int rem   = s / NC8P;
        int wv    = rem % WW;
        int ri    = rem / WW;
        int g     = (gslot & ~7) | ((gslot & 7) ^ (wv & 7));
        if (g >= NC8R) continue;                   // never-read pad slot
        int r  = r0 - PAD + ri;
        int cl = wv - PAD;
        f16x8 val = {};
        if ((unsigned)r < 32u && (unsigned)cl < 32u)
            val = ld_act16(&Xin[(size_t)(img * 1024 + r * 32 + cl) * ICS + g * 8]);
        *(f16x8*)&lds[(size_t)s * 16] = val;
    }
    __syncthreads();

    f32x4 acc[MMv][2] = {};
#pragma unroll
    for (int tap = 0; tap < TAPS; ++tap) {
        if (TAPS > 1 && tap + 2 < TAPS) {          // prefetch 2 ahead
            if ((tap + 2) % 3 == 0)      loadw(w0, tap + 2);
            else if ((tap + 2) % 3 == 1) loadw(w1, tap + 2);
            else                         loadw(w2, tap + 2);
        }
        const f16x8 (&wt)[KC][MMv] =
            (tap % 3 == 0) ? w0 : (tap % 3 == 1) ? w1 : w2;
        const int dy = (TAPS == 9) ? tap / 3 - 1 : 0;
        const int dx = (TAPS == 9) ? tap % 3 - 1 : 0;
        const int ri = wave + PAD + dy;
#pragma unroll
        for (int kc = 0; kc < KC; ++kc) {
            const int kcg = kc * 4 + lq;
            f16x8 b[2];
#pragma unroll
            for (int n = 0; n < 2; ++n) {
                int wv    = n * 16 + ln + PAD + dx;
                int gslot = (kcg & ~7) | ((kcg & 7) ^ (wv & 7));
                b[n] = *(const f16x8*)&lds[(size_t)((ri * WW + wv) * NC8P + gslot) * 16];
            }
#pragma unroll
            for (int m = 0; m < MMv; ++m)
#pragma unroll
                for (int n = 0; n < 2; ++n)
                    acc[m][n] = __builtin_amdgcn_mfma_f32_16x16x32_f16(
                        wt[kc][m], b[n], acc[m][n], 0, 0, 0);
        }
    }

    // ---- epilogue ----
    const int prow = r0 + wave;
#pragma unroll
    for (int m = 0; m < MMv; ++m) {
        const int oc = ocg + m * 16 + lq * 4;
        float b0 = 0.f, b1 = 0.f, b2 = 0.f, b3 = 0.f;
        if (TAPS == 9) {
            float4 bv = *(const float4*)&bias[oc];
            b0 = bv.x; b1 = bv.y; b2 = bv.z; b3 = bv.w;
        }
#pragma unroll
        for (int n = 0; n < 2; ++n) {
            float v0 = acc[m][n][0] * scale + b0;
            float v1 = acc[m][n][1] * scale + b1;
            float v2 = acc[m][n][2] * scale + b2;
            float v3 = acc[m][n][3] * scale + b3;
            if (RELU) {
                v0 = fmaxf(v0, 0.f); v1 = fmaxf(v1, 0.f);
                v2 = fmaxf(v2, 0.f); v3 = fmaxf(v3, 0.f);
            }
            if (OUT32) {
                size_t ob = (size_t)(img * 192 + oc) * 1024 + prow * 32 + n * 16 + ln;
                Out32[ob]        = v0;
                Out32[ob + 1024] = v1;
                Out32[ob + 2048] = v2;
                Out32[ob + 3072] = v3;
            } else {
                const int p = img * 1024 + prow * 32 + n * 16 + ln;
                f16* op = &Out[(size_t)p * OCS + oc];
                if (ACCUM) {
                    f16x4 old = ld_act8(op);
                    v0 += (float)old[0]; v1 += (float)old[1];
                    v2 += (float)old[2]; v3 += (float)old[3];
                }
                f16x4 hv;
                hv[0] = (f16)v0; hv[1] = (f16)v1; hv[2] = (f16)v2; hv[3] = (f16)v3;
                st_act8(op, hv);
            }
        }
    }
}

// ---------------------------------------------------------------------------
// Persistent kernel: all 225 layers. 256 WGs = 8 images x 32 WGs.
// ---------------------------------------------------------------------------
__global__ __launch_bounds__(256) void persist_k(
    const f16* __restrict__ WH, const f16* __restrict__ MH,
    const float* __restrict__ BS, f16* __restrict__ XA, f16* __restrict__ XB,
    f16* __restrict__ H1, f16* __restrict__ H2, float* __restrict__ out,
    unsigned* __restrict__ bar)
{
    __shared__ __align__(16) char lds[52224];     // max: conv 6*34*16*16B
    const int wg    = blockIdx.x;
    const int img   = wg >> 5;
    const int local = wg & 31;
    unsigned* ctr = &bar[img * 16];
    unsigned gen = 0;

    for (int blk = 0; blk < 32; ++blk) {
        const size_t w0 = (size_t)blk * 737280;
        const size_t b0 = (size_t)blk * 704;
        f16* cur = (blk & 1) ? XB : XA;
        f16* nxt = (blk & 1) ? XA : XB;

        layer<2, 128, 12, 9, true, false, false>(lds, img, local, cur + 96, 192,
            WH + w0 + 0,      BS + b0 + 0,   H1, 128, nullptr, 1.f);
        img_barrier(ctr, ++gen * 32u);
        layer<2, 128, 16, 9, true, false, false>(lds, img, local, H1, 128,
            WH + w0 + 110592, BS + b0 + 128, H2, 128, nullptr, 1.f);
        img_barrier(ctr, ++gen * 32u);
        layer<2, 96, 16, 9, false, true, false>(lds, img, local, H2, 128,
            WH + w0 + 258048, BS + b0 + 256, cur, 192, nullptr, 1.f);
        img_barrier(ctr, ++gen * 32u);
        layer<2, 128, 12, 9, true, false, false>(lds, img, local, cur, 192,
            WH + w0 + 368640, BS + b0 + 352, H1, 128, nullptr, 1.f);
        img_barrier(ctr, ++gen * 32u);
        layer<2, 128, 16, 9, true, false, false>(lds, img, local, H1, 128,
            WH + w0 + 479232, BS + b0 + 480, H2, 128, nullptr, 1.f);
        img_barrier(ctr, ++gen * 32u);
        layer<2, 96, 16, 9, false, true, false>(lds, img, local, H2, 128,
            WH + w0 + 626688, BS + b0 + 608, cur + 96, 192, nullptr, 1.f);
        img_barrier(ctr, ++gen * 32u);
        if (blk < 31)
            layer<3, 192, 24, 1, false, false, false>(lds, img, local, cur, 192,
                MH + (size_t)blk * 36864, nullptr, nxt, 192, nullptr, 0.5f);
        else
            layer<3, 192, 24, 1, false, false, true>(lds, img, local, cur, 192,
                MH + (size_t)blk * 36864, nullptr, nullptr, 192, out,
                2147483648.f /* 2^31 */);
        img_barrier(ctr, ++gen * 32u);
    }
}

// ---------------------------------------------------------------------------
extern "C" void kernel_launch(void* const* d_in, const int* in_sizes, int n_in,
                              void* d_out, int out_size, void* d_ws, size_t ws_size,
                              hipStream_t stream)
{
    const float* x     = (const float*)d_in[0];
    const float* mu    = (const float*)d_in[1];
    const float* sigma = (const float*)d_in[2];
    const float* wf    = (const float*)d_in[3];
    const float* bf    = (const float*)d_in[4];
    const float* mf    = (const float*)d_in[5];
    const int*   perm  = (const int*)d_in[6];
    float*       out   = (float*)d_out;

    char* ws = (char*)d_ws;
    f16*      WH  = (f16*)(ws);                  // 47,185,920 B
    f16*      MH  = (f16*)(ws + 47185920);       //  2,359,296 B
    float*    BS  = (float*)(ws + 49545216);     //     90,112 B
    f16*      XA  = (f16*)(ws + 49635328);       //  3,145,728 B
    f16*      XB  = (f16*)(ws + 52781056);       //  3,145,728 B
    f16*      H1  = (f16*)(ws + 55926784);       //  2,097,152 B
    f16*      H2  = (f16*)(ws + 58023936);       //  2,097,152 B
    unsigned* BAR = (unsigned*)(ws + 60121088);  //      4,096 B

    hipMemsetAsync(BAR, 0, 4096, stream);

    wconv_k   <<<dim3(8, 192), 256, 0, stream>>>(wf, WH);
    mconv_k   <<<dim3(576),    256, 0, stream>>>(mf, MH);
    bconv_k   <<<dim3(88),     256, 0, stream>>>(bf, BS, 22528);
    prologue_k<<<dim3(768),    256, 0, stream>>>(x, mu, sigma, perm, XA);

    persist_k<<<dim3(256), 256, 0, stream>>>(WH, MH, BS, XA, XB, H1, H2, out, BAR);
}